// Round 18
// baseline (210.172 us; speedup 1.0000x reference)
//
#include <hip/hip_runtime.h>
#include <math.h>

#define BB 32
#define NN 128
#define DD 64
#define EE (NN*NN)          // 16384
#define EPSI 1e-5f

typedef __attribute__((ext_vector_type(8))) short bf16x8;   // 8 bf16 (4 VGPRs)
typedef __attribute__((ext_vector_type(4))) short s16x4;    // 4 bf16 (2 VGPRs)
typedef __attribute__((ext_vector_type(4))) float f32x4;

// lgkmcnt(0)-only wait (NOT s_waitcnt 0: that drains vmcnt too -> store stalls)
#define LGKM0() do { asm volatile("s_waitcnt lgkmcnt(0)" ::: "memory"); \
                     __builtin_amdgcn_sched_barrier(0); } while (0)

__device__ __forceinline__ short f2bf(float f) {
    union { float f; unsigned u; } v; v.f = f;
    unsigned u = v.u;
    unsigned r = (u + 0x7FFFu + ((u >> 16) & 1u)) >> 16;    // RNE
    return (short)r;
}
__device__ __forceinline__ float bf2f(short s) {
    union { unsigned u; float f; } v; v.u = ((unsigned)(unsigned short)s) << 16;
    return v.f;
}
__device__ __forceinline__ float elu(float v) {
    return v > 0.f ? v : __expf(v) - 1.f;     // v_exp_f32 path
}

// ---------------------------------------------------------------------------
// k_node (+ folded fold): blocks [0, B*N): per (b,n) row:
//   z_h = x @ Wh^T ; Ps in j-fragment layout PsJ + legacy PsT ; Pd plain +
//   legacy PdT ; s,t scalars.
// blocks [B*N, B*N+64): fold — M = Wp_e @ We fragment-major (MbT/wfT).
__global__ void k_node(const float* __restrict__ x, const float* __restrict__ Wh,
                       const float* __restrict__ Wp, const float* __restrict__ We,
                       const float* __restrict__ Wa,
                       float* __restrict__ zh,
                       float* __restrict__ PsJ, float* __restrict__ PdP,
                       float* __restrict__ PsT, float* __restrict__ PdT,
                       float* __restrict__ sO, float* __restrict__ tO,
                       short* __restrict__ MbT, short* __restrict__ wfT)
{
    const int row = blockIdx.x;
    const int d = threadIdx.x;           // 0..63
    if (row >= BB*NN) {                  // ---- fold tail blocks ----
        const int ff = row - BB*NN;      // 0..63 == M row d'
        float acc = 0.f;
        for (int o = 0; o < DD; ++o)
            acc += Wp[ff*192 + 128 + o] * We[o*DD + d];
        MbT[(((ff >> 4)*2 + (d >> 5))*64 + (ff & 15) + ((d >> 3) & 3)*16)*8 + (d & 7)]
            = f2bf(acc);
        if (ff == 0) {
            for (int q = 0; q < 16; ++q) wfT[d*16 + q] = 0;
            __syncthreads();
            float aw = 0.f;
            for (int o = 0; o < DD; ++o)
                aw += Wa[128 + o] * We[o*DD + d];
            wfT[((d >> 5)*64 + ((d >> 3) & 3)*16)*8 + (d & 7)] = f2bf(aw);
        }
        return;
    }
    const int b = row >> 7, n = row & 127;
    __shared__ float xr[DD];
    __shared__ float zr[DD];
    xr[d] = x[row*DD + d];
    __syncthreads();
    float acc = 0.f;
#pragma unroll
    for (int k = 0; k < DD; ++k) acc += xr[k] * Wh[d*DD + k];
    zr[d] = acc;
    zh[row*DD + d] = acc;
    __syncthreads();
    float a0 = 0.f, a1 = 0.f;
#pragma unroll
    for (int o = 0; o < DD; ++o) {
        float z = zr[o];
        a0 += Wp[d*192 + o]      * z;
        a1 += Wp[d*192 + 64 + o] * z;
    }
    // PsJ: C-frag layout keyed by j-tile: row_in_tile = n&15 -> (lg,q); col d.
    {
        const int rt = n & 15;
        PsJ[(((b*8 + (n >> 4))*4 + (d >> 4))*64 + (rt >> 2)*16 + (d & 15))*4 + (rt & 3)] = a0;
        PdP[row*DD + d] = a1;
    }
    // legacy (b-row fragment) layouts for the non-dense fallback
    const int fi = ((b >> 4)*4 + (d >> 4))*256 + (((b >> 2) & 3)*16 + (d & 15))*4 + (b & 3);
    PsT[n*2048 + fi] = a0;
    PdT[n*2048 + fi] = a1;
    float sv = zr[d] * Wa[d];
    float tv = zr[d] * Wa[64 + d];
#pragma unroll
    for (int off = 32; off; off >>= 1) {
        sv += __shfl_xor(sv, off);
        tv += __shfl_xor(tv, off);
    }
    if (d == 0) { sO[row] = sv; tO[row] = tv; }
}

// ---------------------------------------------------------------------------
// k_eb<LP>: b-major edge GEMM pass — ALL DRAM streams dense.
// grid = B*128 blocks (b = blk>>7, e-chunk = (blk&127)*128); 4 waves; wave wv
// owns rows e = echunk + wv*32 .. +31 (x 64 d). i0 = blk&127; j = wv*32 + r.
//   z = A @ M^T + Ps[b,j] + Pd[b,i0]     (A: LP==0 raw fp32 edge (B,E,D);
//                                          LP==1 bf16 z1 with BN1+ELU on stage)
//   u[b,e] = A . w  (5th MFMA B-tile)
//   BN partials (per (e,b): sum/sumsq over 64 d) -> sps/spq  [no atomics]
//   z-out: PRE-BN result, bf16 (B,E,D), dense 4KB/wave (in-place safe for LP==1:
//   each wave reads exactly the rows it later writes; reads complete first).
template <int LP>
__global__ __launch_bounds__(256, 4) void k_eb(
    const void* einv,
    const short* __restrict__ MbT,   // (8,64,8) bf16 fragment-major
    const short* __restrict__ wfT,   // (2,64,8) bf16 fragment-major
    const float* __restrict__ PsJ,   // (B,8,4,64,4) j-fragment layout
    const float* __restrict__ PdP,   // (B,N,D) plain
    const float* __restrict__ sc1, const float* __restrict__ sh1,  // LP==1 only
    float* __restrict__ sps, float* __restrict__ spq,  // [e*32+b]
    short* __restrict__ zout,        // bf16 (B,E,D)
    float* __restrict__ uout)
{
    __shared__ __align__(16) char SM[4][8704];   // per-wave: stage 4608B / Z 8704B
    const int t  = threadIdx.x;
    const int l  = t & 63;
    const int wv = t >> 6;
    const int lr = l & 15;
    const int lg = l >> 4;
    const int b  = blockIdx.x >> 7;
    const int i0 = blockIdx.x & 127;
    const int e0w = i0*128 + wv*32;          // wave's first channel
    short (*As)[72] = reinterpret_cast<short (*)[72]>(&SM[wv][0]);
    float (*Z)[68]  = reinterpret_cast<float (*)[68]>(&SM[wv][0]);

    // ---- stage A (dense reads) ----
    if constexpr (LP == 0) {
        const float* base = (const float*)einv + ((size_t)b*EE + e0w)*DD;
        float4 sv[8];
#pragma unroll
        for (int it = 0; it < 8; ++it)
            sv[it] = *reinterpret_cast<const float4*>(base + it*256 + l*4);   // 1KB dense
#pragma unroll
        for (int it = 0; it < 8; ++it) {
            const int r  = it*4 + (l >> 4);
            const int d0 = (l & 15)*4;
            s16x4 o;
            o[0] = f2bf(sv[it].x); o[1] = f2bf(sv[it].y);
            o[2] = f2bf(sv[it].z); o[3] = f2bf(sv[it].w);
            *reinterpret_cast<s16x4*>(&As[r][d0]) = o;
        }
    } else {
        const short* base = (const short*)einv + ((size_t)b*EE + e0w)*DD;
#pragma unroll
        for (int it = 0; it < 4; ++it) {
            const int r  = (l >> 3) + 8*it;
            const int d0 = (l & 7)*8;
            bf16x8 v = *reinterpret_cast<const bf16x8*>(base + r*DD + d0);    // 1KB dense
            const float scv = sc1[e0w + r], shv = sh1[e0w + r];
            bf16x8 o;
#pragma unroll
            for (int j = 0; j < 8; ++j)
                o[j] = f2bf(elu(bf2f(v[j])*scv + shv));
            *reinterpret_cast<bf16x8*>(&As[r][d0]) = o;
        }
    }
    LGKM0();                                 // own ds_writes drained (wave-private)

    // ---- A fragments from LDS ----
    bf16x8 afr[2][2];
#pragma unroll
    for (int m = 0; m < 2; ++m)
#pragma unroll
        for (int s = 0; s < 2; ++s)
            afr[m][s] = *reinterpret_cast<const bf16x8*>(&As[16*m + lr][s*32 + lg*8]);

    // ---- B/w fragments (lane-dense) ----
    bf16x8 bfr[4][2];
#pragma unroll
    for (int n = 0; n < 4; ++n)
#pragma unroll
        for (int s = 0; s < 2; ++s)
            bfr[n][s] = *reinterpret_cast<const bf16x8*>(MbT + ((n*2 + s)*64 + l)*8);
    bf16x8 wfrag[2];
#pragma unroll
    for (int s = 0; s < 2; ++s)
        wfrag[s] = *reinterpret_cast<const bf16x8*>(wfT + (s*64 + l)*8);

    // ---- acc init = PsJ (lane-dense float4) + PdP (row-constant) ----
    f32x4 acc[2][4];
    f32x4 uacc[2];
    float pd[4];
#pragma unroll
    for (int n = 0; n < 4; ++n)
        pd[n] = PdP[((size_t)(b*NN + i0))*DD + 16*n + lr];
#pragma unroll
    for (int m = 0; m < 2; ++m) {
        uacc[m] = (f32x4){0.f, 0.f, 0.f, 0.f};
        const int jb = wv*2 + m;
#pragma unroll
        for (int n = 0; n < 4; ++n) {
            const float4 p = *reinterpret_cast<const float4*>(
                PsJ + (((b*8 + jb)*4 + n)*64 + l)*4);
            acc[m][n] = (f32x4){p.x + pd[n], p.y + pd[n], p.z + pd[n], p.w + pd[n]};
        }
    }

    // ---- MFMA: 16 z-tiles + 4 u-tiles ----
#pragma unroll
    for (int m = 0; m < 2; ++m) {
#pragma unroll
        for (int n = 0; n < 4; ++n)
            acc[m][n] = __builtin_amdgcn_mfma_f32_16x16x32_bf16(afr[m][0], bfr[n][0], acc[m][n], 0, 0, 0);
        uacc[m] = __builtin_amdgcn_mfma_f32_16x16x32_bf16(afr[m][0], wfrag[0], uacc[m], 0, 0, 0);
#pragma unroll
        for (int n = 0; n < 4; ++n)
            acc[m][n] = __builtin_amdgcn_mfma_f32_16x16x32_bf16(afr[m][1], bfr[n][1], acc[m][n], 0, 0, 0);
        uacc[m] = __builtin_amdgcn_mfma_f32_16x16x32_bf16(afr[m][1], wfrag[1], uacc[m], 0, 0, 0);
    }

    // ---- u store (rows = channels e) ----
    if (lr == 0) {
#pragma unroll
        for (int m = 0; m < 2; ++m)
#pragma unroll
            for (int q = 0; q < 4; ++q)
                uout[(size_t)b*EE + e0w + 16*m + 4*lg + q] = uacc[m][q];
    }

    // ---- BN partials: per row e, sum/sumsq over this wave's 64 d ----
#pragma unroll
    for (int m = 0; m < 2; ++m)
#pragma unroll
        for (int q = 0; q < 4; ++q) {
            float v  = acc[m][0][q] + acc[m][1][q] + acc[m][2][q] + acc[m][3][q];
            float vv = acc[m][0][q]*acc[m][0][q] + acc[m][1][q]*acc[m][1][q]
                     + acc[m][2][q]*acc[m][2][q] + acc[m][3][q]*acc[m][3][q];
#pragma unroll
            for (int off = 1; off < 16; off <<= 1) {
                v  += __shfl_xor(v, off);
                vv += __shfl_xor(vv, off);
            }
            if (lr == 0) {
                const int e = e0w + 16*m + 4*lg + q;
                sps[(size_t)e*BB + b] = v;
                spq[(size_t)e*BB + b] = vv;
            }
        }

    // ---- repack (pre-BN) + dense bf16 store (B,E,D) ----
    LGKM0();                                 // own frag reads done; reuse section
#pragma unroll
    for (int m = 0; m < 2; ++m)
#pragma unroll
        for (int n = 0; n < 4; ++n)
#pragma unroll
            for (int q = 0; q < 4; ++q)
                Z[16*m + 4*lg + q][16*n + lr] = acc[m][n][q];
    LGKM0();
    short* zo = zout + ((size_t)b*EE + e0w)*DD;
#pragma unroll
    for (int it = 0; it < 4; ++it) {
        const int r  = (l >> 3) + 8*it;
        const int c0 = (l & 7)*8;
        float4 zlo = *reinterpret_cast<float4*>(&Z[r][c0]);
        float4 zhi = *reinterpret_cast<float4*>(&Z[r][c0+4]);
        bf16x8 o;
        o[0]=f2bf(zlo.x); o[1]=f2bf(zlo.y); o[2]=f2bf(zlo.z); o[3]=f2bf(zlo.w);
        o[4]=f2bf(zhi.x); o[5]=f2bf(zhi.y); o[6]=f2bf(zhi.z); o[7]=f2bf(zhi.w);
        *reinterpret_cast<bf16x8*>(zo + r*DD + c0) = o;          // 1KB dense
    }
}

// ---------------------------------------------------------------------------
// k_fs: finalize BN stats: per channel e reduce 32 partials -> sc/sh.
__global__ void k_fs(const float* __restrict__ sps, const float* __restrict__ spq,
                     const float* __restrict__ g, const float* __restrict__ be,
                     float* __restrict__ sc, float* __restrict__ sh)
{
    const int e = blockIdx.x * 256 + threadIdx.x;
    float s = 0.f, q = 0.f;
#pragma unroll
    for (int k = 0; k < BB; k += 4) {
        const float4 a = *reinterpret_cast<const float4*>(sps + (size_t)e*BB + k);
        const float4 c = *reinterpret_cast<const float4*>(spq + (size_t)e*BB + k);
        s += (a.x + a.y) + (a.z + a.w);
        q += (c.x + c.y) + (c.z + c.w);
    }
    const float mean = s * (1.f/2048.f);
    const float var  = q * (1.f/2048.f) - mean*mean;
    const float scv  = g[e] * rsqrtf(var + EPSI);
    sc[e] = scv;
    sh[e] = be[e] - mean*scv;
}

// ---------------------------------------------------------------------------
// k_fin: dense stream: eout fp32 (B,E,D) = elu(z2*sc2[e] + sh2[e]).
__global__ __launch_bounds__(256) void k_fin(const short* __restrict__ z,
                                             const float* __restrict__ sc,
                                             const float* __restrict__ sh,
                                             float* __restrict__ eout)
{
    const size_t base = ((size_t)blockIdx.x * 256 + threadIdx.x) * 8;
    const int e = (int)((base >> 6) & (EE - 1));
    const bf16x8 v = *reinterpret_cast<const bf16x8*>(z + base);
    const float scv = sc[e], shv = sh[e];
    float4 o0, o1;
    o0.x = elu(bf2f(v[0])*scv + shv); o0.y = elu(bf2f(v[1])*scv + shv);
    o0.z = elu(bf2f(v[2])*scv + shv); o0.w = elu(bf2f(v[3])*scv + shv);
    o1.x = elu(bf2f(v[4])*scv + shv); o1.y = elu(bf2f(v[5])*scv + shv);
    o1.z = elu(bf2f(v[6])*scv + shv); o1.w = elu(bf2f(v[7])*scv + shv);
    *reinterpret_cast<float4*>(eout + base)     = o0;
    *reinterpret_cast<float4*>(eout + base + 4) = o1;
}

// ---------------------------------------------------------------------------
// k_edge_f: legacy e-tiled kernel (fp32 in/out, in-place) — fallback only.
__global__ __launch_bounds__(256, 4) void k_edge_f(
    const float* ein, const short* __restrict__ MbT, const short* __restrict__ wfT,
    const float* __restrict__ PsT, const float* __restrict__ PdT,
    const float* __restrict__ ge, const float* __restrict__ be,
    float* eout, float* __restrict__ uout)
{
    __shared__ __align__(16) char SM[4][8704];
    const int t = threadIdx.x, l = t & 63, wv = t >> 6;
    const int lr = l & 15, lg = l >> 4;
    const int e = blockIdx.x * 4 + wv;
    const int i0 = e >> 7, j0 = e & 127;
    short (*As)[72] = reinterpret_cast<short (*)[72]>(&SM[wv][0]);
    float (*Z)[68]  = reinterpret_cast<float (*)[68]>(&SM[wv][0]);
    float4 sv[8];
#pragma unroll
    for (int it = 0; it < 8; ++it) {
        const int b = 4*it + (l >> 4);
        sv[it] = *reinterpret_cast<const float4*>(ein + ((size_t)b*EE + e)*DD + (l & 15)*4);
    }
#pragma unroll
    for (int it = 0; it < 8; ++it) {
        const int b = 4*it + (l >> 4);
        s16x4 o;
        o[0]=f2bf(sv[it].x); o[1]=f2bf(sv[it].y); o[2]=f2bf(sv[it].z); o[3]=f2bf(sv[it].w);
        *reinterpret_cast<s16x4*>(&As[b][(l & 15)*4]) = o;
    }
    LGKM0();
    bf16x8 afr[2][2];
#pragma unroll
    for (int m = 0; m < 2; ++m)
#pragma unroll
        for (int s = 0; s < 2; ++s)
            afr[m][s] = *reinterpret_cast<const bf16x8*>(&As[16*m + lr][s*32 + lg*8]);
    bf16x8 bfr[4][2];
#pragma unroll
    for (int n = 0; n < 4; ++n)
#pragma unroll
        for (int s = 0; s < 2; ++s)
            bfr[n][s] = *reinterpret_cast<const bf16x8*>(MbT + ((n*2 + s)*64 + l)*8);
    bf16x8 wfrag[2];
#pragma unroll
    for (int s = 0; s < 2; ++s)
        wfrag[s] = *reinterpret_cast<const bf16x8*>(wfT + (s*64 + l)*8);
    f32x4 acc[2][4]; f32x4 uacc[2];
    {
        const float* psb = PsT + j0*2048;
        const float* pdb = PdT + i0*2048;
#pragma unroll
        for (int m = 0; m < 2; ++m) {
            uacc[m] = (f32x4){0.f,0.f,0.f,0.f};
#pragma unroll
            for (int n = 0; n < 4; ++n) {
                const float4 a = *reinterpret_cast<const float4*>(psb + (m*4+n)*256 + l*4);
                const float4 c = *reinterpret_cast<const float4*>(pdb + (m*4+n)*256 + l*4);
                acc[m][n] = (f32x4){a.x+c.x, a.y+c.y, a.z+c.z, a.w+c.w};
            }
        }
    }
#pragma unroll
    for (int m = 0; m < 2; ++m) {
#pragma unroll
        for (int n = 0; n < 4; ++n)
            acc[m][n] = __builtin_amdgcn_mfma_f32_16x16x32_bf16(afr[m][0], bfr[n][0], acc[m][n], 0, 0, 0);
        uacc[m] = __builtin_amdgcn_mfma_f32_16x16x32_bf16(afr[m][0], wfrag[0], uacc[m], 0, 0, 0);
#pragma unroll
        for (int n = 0; n < 4; ++n)
            acc[m][n] = __builtin_amdgcn_mfma_f32_16x16x32_bf16(afr[m][1], bfr[n][1], acc[m][n], 0, 0, 0);
        uacc[m] = __builtin_amdgcn_mfma_f32_16x16x32_bf16(afr[m][1], wfrag[1], uacc[m], 0, 0, 0);
    }
    float s1 = 0.f, s2 = 0.f;
#pragma unroll
    for (int m = 0; m < 2; ++m)
#pragma unroll
        for (int n = 0; n < 4; ++n)
#pragma unroll
            for (int q = 0; q < 4; ++q) { float v = acc[m][n][q]; s1 += v; s2 += v*v; }
#pragma unroll
    for (int off = 1; off < 64; off <<= 1) {
        s1 += __shfl_xor(s1, off);
        s2 += __shfl_xor(s2, off);
    }
    const float mean = s1 * (1.f/2048.f);
    const float var  = s2 * (1.f/2048.f) - mean*mean;
    const float sc = ge[e] * rsqrtf(var + EPSI);
    const float sh = be[e] - mean*sc;
#pragma unroll
    for (int m = 0; m < 2; ++m)
#pragma unroll
        for (int n = 0; n < 4; ++n)
#pragma unroll
            for (int q = 0; q < 4; ++q)
                acc[m][n][q] = elu(acc[m][n][q]*sc + sh);
    if (lr == 0) {
#pragma unroll
        for (int m = 0; m < 2; ++m)
#pragma unroll
            for (int q = 0; q < 4; ++q)
                uout[(size_t)(16*m + 4*lg + q)*EE + e] = uacc[m][q];
    }
    LGKM0();
#pragma unroll
    for (int m = 0; m < 2; ++m)
#pragma unroll
        for (int n = 0; n < 4; ++n)
#pragma unroll
            for (int q = 0; q < 4; ++q)
                Z[16*m + 4*lg + q][16*n + lr] = acc[m][n][q];
    LGKM0();
#pragma unroll
    for (int it = 0; it < 8; ++it) {
        const int b = lg + 4*it;
        float4 z = *reinterpret_cast<float4*>(&Z[b][lr*4]);
        *reinterpret_cast<float4*>(eout + ((size_t)b*EE + e)*DD + lr*4) = z;
    }
}

// ---------------------------------------------------------------------------
// k_attn: per (b,i): logits = lrelu(s[j]+t[i]+u[b,i*N+j]) -> softmax over j
__global__ void k_attn(const float* __restrict__ sI, const float* __restrict__ tI,
                       const float* __restrict__ u, const float* __restrict__ zh,
                       float* __restrict__ agg)
{
    int blk = blockIdx.x; int b = blk >> 7, i = blk & 127;
    int l = threadIdx.x;
    __shared__ float at[NN];
    float ti = tI[blk];
    float l0 = sI[b*NN + l]      + ti + u[b*EE + i*NN + l];
    float l1 = sI[b*NN + l + 64] + ti + u[b*EE + i*NN + l + 64];
    l0 = l0 >= 0.f ? l0 : 0.01f*l0;
    l1 = l1 >= 0.f ? l1 : 0.01f*l1;
    float mx = fmaxf(l0, l1);
#pragma unroll
    for (int off = 32; off; off >>= 1) mx = fmaxf(mx, __shfl_xor(mx, off));
    float e0 = __expf(l0 - mx), e1 = __expf(l1 - mx);
    float sm = e0 + e1;
#pragma unroll
    for (int off = 32; off; off >>= 1) sm += __shfl_xor(sm, off);
    float inv = 1.f / sm;
    at[l]      = e0 * inv;
    at[l + 64] = e1 * inv;
    __syncthreads();
    const float* zb = zh + (size_t)b*NN*DD + l;
    float a0 = 0.f, a1 = 0.f, a2 = 0.f, a3 = 0.f;
#pragma unroll 4
    for (int j = 0; j < NN; j += 4) {
        a0 += at[j]     * zb[(j)    *DD];
        a1 += at[j + 1] * zb[(j + 1)*DD];
        a2 += at[j + 2] * zb[(j + 2)*DD];
        a3 += at[j + 3] * zb[(j + 3)*DD];
    }
    agg[(b*NN + i)*DD + l] = (a0 + a1) + (a2 + a3);
}

// ---------------------------------------------------------------------------
// k_vbn: vertex BN (channel i over b,d) + residual + ELU
__global__ void k_vbn(const float* __restrict__ agg, const float* __restrict__ xres,
                      const float* __restrict__ gv, const float* __restrict__ bv,
                      float* __restrict__ xout)
{
    int i = blockIdx.x, t = threadIdx.x;
    float vals[8];
    float s1 = 0.f, s2 = 0.f;
#pragma unroll
    for (int q = 0; q < 8; ++q) {
        int m = t + 256*q; int b = m >> 6, d = m & 63;
        float v = agg[(b*NN + i)*DD + d];
        vals[q] = v; s1 += v; s2 += v*v;
    }
#pragma unroll
    for (int off = 1; off < 64; off <<= 1) {
        s1 += __shfl_xor(s1, off);
        s2 += __shfl_xor(s2, off);
    }
    __shared__ float r1[4], r2[4];
    int wv = t >> 6;
    if ((t & 63) == 0) { r1[wv] = s1; r2[wv] = s2; }
    __syncthreads();
    s1 = r1[0] + r1[1] + r1[2] + r1[3];
    s2 = r2[0] + r2[1] + r2[2] + r2[3];
    float mean  = s1 * (1.f/2048.f);
    float var   = s2 * (1.f/2048.f) - mean*mean;
    float scale = gv[i] * rsqrtf(var + EPSI);
    float shift = bv[i] - mean*scale;
#pragma unroll
    for (int q = 0; q < 8; ++q) {
        int m = t + 256*q; int b = m >> 6, d = m & 63;
        float v = vals[q]*scale + shift + xres[(b*NN + i)*DD + d];
        xout[(b*NN + i)*DD + d] = v > 0.f ? v : __expf(v) - 1.f;
    }
}

// ---------------------------------------------------------------------------
extern "C" void kernel_launch(void* const* d_in, const int* in_sizes, int n_in,
                              void* d_out, int out_size, void* d_ws, size_t ws_size,
                              hipStream_t stream)
{
    const float* x    = (const float*)d_in[0];
    const float* edge = (const float*)d_in[1];
    const float* Wh1  = (const float*)d_in[2];
    const float* We1  = (const float*)d_in[3];
    const float* Wp1  = (const float*)d_in[4];
    const float* Wa1  = (const float*)d_in[5];
    const float* Wh2  = (const float*)d_in[6];
    const float* We2  = (const float*)d_in[7];
    const float* Wp2  = (const float*)d_in[8];
    const float* Wa2  = (const float*)d_in[9];
    const float* gv1  = (const float*)d_in[10];
    const float* bv1  = (const float*)d_in[11];
    const float* ge1  = (const float*)d_in[12];
    const float* be1  = (const float*)d_in[13];
    const float* gv2  = (const float*)d_in[14];
    const float* bv2  = (const float*)d_in[15];
    const float* ge2  = (const float*)d_in[16];
    const float* be2  = (const float*)d_in[17];

    float* xout = (float*)d_out;                    // (B,N,D)
    float* eout = (float*)d_out + BB*NN*DD;         // (B,E,D) final edge output

    float* ws  = (float*)d_ws;
    short* MbT = (short*)ws;  ws += DD*DD/2;        // 8 KB
    short* wfT = (short*)ws;  ws += 1024/2;         // 2 KB
    float* zh  = ws;  ws += BB*NN*DD;               // 1 MB
    float* PsJ = ws;  ws += BB*NN*DD;               // 1 MB
    float* PdP = ws;  ws += BB*NN*DD;               // 1 MB
    float* PsT = ws;  ws += NN*BB*DD;               // 1 MB (fallback)
    float* PdT = ws;  ws += NN*BB*DD;               // 1 MB (fallback)
    float* sb  = ws;  ws += BB*NN;
    float* tb  = ws;  ws += BB*NN;
    float* ub  = ws;  ws += BB*EE;                  // 2 MB
    float* agg = ws;  ws += BB*NN*DD;               // 1 MB
    float* x1  = ws;  ws += BB*NN*DD;               // 1 MB
    float* sps = ws;  ws += EE*BB;                  // 2 MB
    float* spq = ws;  ws += EE*BB;                  // 2 MB
    float* sc  = ws;  ws += EE;                     // 64 KB
    float* sh  = ws;  ws += EE;                     // 64 KB
    short* z12 = (short*)ws;                        // bf16 (B,E,D), 67 MB
    const size_t need = ((size_t)(ws - (float*)d_ws))*4 + (size_t)BB*EE*DD*2;

    const bool dense = (ws_size >= need);

    // ----- layer 1 -----
    k_node<<<BB*NN + 64, 64, 0, stream>>>(x, Wh1, Wp1, We1, Wa1, zh, PsJ, PdP, PsT, PdT, sb, tb, MbT, wfT);
    if (dense) {
        k_eb<0><<<BB*128, 256, 0, stream>>>(edge, MbT, wfT, PsJ, PdP, nullptr, nullptr, sps, spq, z12, ub);
        k_fs<<<EE/256, 256, 0, stream>>>(sps, spq, ge1, be1, sc, sh);
    } else {
        k_edge_f<<<EE/4, 256, 0, stream>>>(edge, MbT, wfT, PsT, PdT, ge1, be1, eout, ub);
    }
    k_attn<<<BB*NN, 64, 0, stream>>>(sb, tb, ub, zh, agg);
    k_vbn<<<NN, 256, 0, stream>>>(agg, x, gv1, bv1, x1);
    // ----- layer 2 -----
    k_node<<<BB*NN + 64, 64, 0, stream>>>(x1, Wh2, Wp2, We2, Wa2, zh, PsJ, PdP, PsT, PdT, sb, tb, MbT, wfT);
    if (dense) {
        k_eb<1><<<BB*128, 256, 0, stream>>>(z12, MbT, wfT, PsJ, PdP, sc, sh, sps, spq, z12, ub);
        k_fs<<<EE/256, 256, 0, stream>>>(sps, spq, ge2, be2, sc, sh);
        k_fin<<<16384, 256, 0, stream>>>(z12, sc, sh, eout);
    } else {
        k_edge_f<<<EE/4, 256, 0, stream>>>(eout, MbT, wfT, PsT, PdT, ge2, be2, eout, ub);
    }
    k_attn<<<BB*NN, 64, 0, stream>>>(sb, tb, ub, zh, agg);
    k_vbn<<<NN, 256, 0, stream>>>(agg, x1, gv2, bv2, xout);
}

// Round 19
// 183.146 us; speedup vs baseline: 1.1476x; 1.1476x over previous
//
#include <hip/hip_runtime.h>
#include <math.h>

#define BB 32
#define NN 128
#define DD 64
#define EE (NN*NN)          // 16384
#define EPSI 1e-5f

typedef __attribute__((ext_vector_type(8))) short bf16x8;   // 8 bf16 (4 VGPRs)
typedef __attribute__((ext_vector_type(4))) short s16x4;    // 4 bf16 (2 VGPRs)
typedef __attribute__((ext_vector_type(4))) float f32x4;

// lgkmcnt(0)-only wait (NOT s_waitcnt 0: that drains vmcnt too -> store stalls)
#define LGKM0() do { asm volatile("s_waitcnt lgkmcnt(0)" ::: "memory"); \
                     __builtin_amdgcn_sched_barrier(0); } while (0)

__device__ __forceinline__ short f2bf(float f) {
    union { float f; unsigned u; } v; v.f = f;
    unsigned u = v.u;
    unsigned r = (u + 0x7FFFu + ((u >> 16) & 1u)) >> 16;    // RNE
    return (short)r;
}
__device__ __forceinline__ float bf2f(short s) {
    union { unsigned u; float f; } v; v.u = ((unsigned)(unsigned short)s) << 16;
    return v.f;
}
__device__ __forceinline__ float elu(float v) {
    return v > 0.f ? v : __expf(v) - 1.f;     // v_exp_f32 path
}

// ---------------------------------------------------------------------------
// k_node (+ folded fold): blocks [0, B*N): per (b,n) row:
//   z_h = x @ Wh^T ; PsT/PdT in MFMA C-fragment layout ; s,t scalars.
// blocks [B*N, B*N+64): fold — M = Wp_e @ We stored FRAGMENT-MAJOR:
//   MbT[((n*2+s)*64 + lane)*8 + j] = M[d=16n+(lane&15)][k=s*32+(lane>>4)*8+j]
//   so k_edge's B-loads are lane-dense (1 segment per instruction).
//   wfT likewise (col0 = w, other lanes pre-zeroed -> no branch in k_edge).
__global__ void k_node(const float* __restrict__ x, const float* __restrict__ Wh,
                       const float* __restrict__ Wp, const float* __restrict__ We,
                       const float* __restrict__ Wa,
                       float* __restrict__ zh, float* __restrict__ PsT,
                       float* __restrict__ PdT, float* __restrict__ sO,
                       float* __restrict__ tO,
                       short* __restrict__ MbT, short* __restrict__ wfT)
{
    const int row = blockIdx.x;
    const int d = threadIdx.x;           // 0..63
    if (row >= BB*NN) {                  // ---- fold tail blocks ----
        const int ff = row - BB*NN;      // 0..63 == M row d'
        float acc = 0.f;
        for (int o = 0; o < DD; ++o)
            acc += Wp[ff*192 + 128 + o] * We[o*DD + d];
        // fragment-major scatter: n=ff>>4, lr=ff&15, s=d>>5, lg=(d>>3)&3, j=d&7
        MbT[(((ff >> 4)*2 + (d >> 5))*64 + (ff & 15) + ((d >> 3) & 3)*16)*8 + (d & 7)]
            = f2bf(acc);
        if (ff == 0) {
            for (int q = 0; q < 16; ++q) wfT[d*16 + q] = 0;   // zero 1024 shorts
            __syncthreads();
            float aw = 0.f;
            for (int o = 0; o < DD; ++o)
                aw += Wa[128 + o] * We[o*DD + d];
            // lane = lg*16 (lr==0 slot)
            wfT[((d >> 5)*64 + ((d >> 3) & 3)*16)*8 + (d & 7)] = f2bf(aw);
        }
        return;
    }
    const int b = row >> 7, n = row & 127;
    __shared__ float xr[DD];
    __shared__ float zr[DD];
    xr[d] = x[row*DD + d];
    __syncthreads();
    float acc = 0.f;
#pragma unroll
    for (int k = 0; k < DD; ++k) acc += xr[k] * Wh[d*DD + k];
    zr[d] = acc;
    zh[row*DD + d] = acc;
    __syncthreads();
    float a0 = 0.f, a1 = 0.f;
#pragma unroll
    for (int o = 0; o < DD; ++o) {
        float z = zr[o];
        a0 += Wp[d*192 + o]      * z;
        a1 += Wp[d*192 + 64 + o] * z;
    }
    const int fi = ((b >> 4)*4 + (d >> 4))*256 + (((b >> 2) & 3)*16 + (d & 15))*4 + (b & 3);
    PsT[n*2048 + fi] = a0;
    PdT[n*2048 + fi] = a1;
    float sv = zr[d] * Wa[d];
    float tv = zr[d] * Wa[64 + d];
#pragma unroll
    for (int off = 32; off; off >>= 1) {
        sv += __shfl_xor(sv, off);
        tv += __shfl_xor(tv, off);
    }
    if (d == 0) { sO[row] = sv; tO[row] = tv; }
}

// ---------------------------------------------------------------------------
// k_edge (v8 body + lane-dense fragment I/O):
//   z = edge @ M^T + Ps[b,j] + Pd[b,i] -> BN(per-e over b,d) -> ELU
//   u[b,e] = edge . w  via a 5th MFMA B-tile (col0 = w)
// 256 threads = 4 waves; wave wv owns channel e = 4*blk + wv (32 b x 64 d).
// INM==0: A fp32 (B,E,D); contiguous 1KB runs staged into bf16 LDS As.
// INM==1: A in A-FRAGMENT-MAJOR bf16 (E, 8frag, 64lane, 8) -> 4 dense loads.
// B/w: fragment-major MbT/wfT -> 10 dense loads (was ~130 gather segments).
// OUTM==0: fp32 (B,E,D) (d_out), float4 rows via LDS repack.
// OUTM==1: A-fragment-major bf16 intermediate (for the next layer's INM==1).
template <int INM, int OUTM>
__global__ __launch_bounds__(256, 4) void k_edge(
    const void* einv,
    const short* __restrict__ MbT,   // (8,64,8) bf16 fragment-major
    const short* __restrict__ wfT,   // (2,64,8) bf16 fragment-major
    const float* __restrict__ PsT,   // (N, 2048) fragment layout
    const float* __restrict__ PdT,   // (N, 2048) fragment layout
    const float* __restrict__ ge, const float* __restrict__ be,
    void* eoutv, float* __restrict__ uout)
{
    __shared__ short As[4][32][72];  // 18,432 B; staged A; reused as repack buf
    const int t  = threadIdx.x;
    const int l  = t & 63;
    const int wv = t >> 6;
    const int lr = l & 15;
    const int lg = l >> 4;
    const int e0 = blockIdx.x * 4;
    const int e  = e0 + wv;
    const int i0 = e >> 7, j0 = e & 127;

    // ---- A fragments ----
    bf16x8 afr[2][2];                 // [m][k-half]
    if constexpr (INM == 0) {
        const float* ein = (const float*)einv;
        const int tq = (t >> 4) & 3;          // e-local
        const int d0 = (t & 15) * 4;
        float4 sv[8];
#pragma unroll
        for (int it = 0; it < 8; ++it) {
            const int b = it*4 + wv;
            sv[it] = *reinterpret_cast<const float4*>(
                         ein + ((size_t)b*EE + e0 + tq)*DD + d0);
        }
#pragma unroll
        for (int it = 0; it < 8; ++it) {
            const int b = it*4 + wv;
            s16x4 o;
            o[0] = f2bf(sv[it].x); o[1] = f2bf(sv[it].y);
            o[2] = f2bf(sv[it].z); o[3] = f2bf(sv[it].w);
            *reinterpret_cast<s16x4*>(&As[tq][b][d0]) = o;
        }
        __syncthreads();
#pragma unroll
        for (int m = 0; m < 2; ++m)
#pragma unroll
            for (int s = 0; s < 2; ++s)
                afr[m][s] = *reinterpret_cast<const bf16x8*>(
                                &As[wv][16*m + lr][s*32 + lg*8]);
    } else {
        const short* ein = (const short*)einv + (size_t)e*BB*DD;  // frag-major blk
#pragma unroll
        for (int m = 0; m < 2; ++m)
#pragma unroll
            for (int s = 0; s < 2; ++s)
                afr[m][s] = *reinterpret_cast<const bf16x8*>(
                                ein + ((m*2 + s)*64 + l)*8);      // lane-dense 1KB
    }

    // ---- B fragments + w fragment: lane-dense fragment-major loads ----
    bf16x8 bfr[4][2];
#pragma unroll
    for (int n = 0; n < 4; ++n)
#pragma unroll
        for (int s = 0; s < 2; ++s)
            bfr[n][s] = *reinterpret_cast<const bf16x8*>(MbT + ((n*2 + s)*64 + l)*8);
    bf16x8 wfrag[2];
#pragma unroll
    for (int s = 0; s < 2; ++s)
        wfrag[s] = *reinterpret_cast<const bf16x8*>(wfT + (s*64 + l)*8);

    // ---- acc init = PsT[j0] + PdT[i0]: dense fragment-layout loads ----
    f32x4 acc[2][4];
    f32x4 uacc[2];
    {
        const float* psb = PsT + j0*2048;
        const float* pdb = PdT + i0*2048;
#pragma unroll
        for (int m = 0; m < 2; ++m) {
            uacc[m] = (f32x4){0.f, 0.f, 0.f, 0.f};
#pragma unroll
            for (int n = 0; n < 4; ++n) {
                const float4 a = *reinterpret_cast<const float4*>(psb + (m*4+n)*256 + l*4);
                const float4 c = *reinterpret_cast<const float4*>(pdb + (m*4+n)*256 + l*4);
                acc[m][n] = (f32x4){a.x+c.x, a.y+c.y, a.z+c.z, a.w+c.w};
            }
        }
    }

    // ---- MFMA: 16 z-tiles + 4 u-tiles ----
#pragma unroll
    for (int m = 0; m < 2; ++m) {
#pragma unroll
        for (int n = 0; n < 4; ++n)
            acc[m][n] = __builtin_amdgcn_mfma_f32_16x16x32_bf16(afr[m][0], bfr[n][0], acc[m][n], 0, 0, 0);
        uacc[m] = __builtin_amdgcn_mfma_f32_16x16x32_bf16(afr[m][0], wfrag[0], uacc[m], 0, 0, 0);
#pragma unroll
        for (int n = 0; n < 4; ++n)
            acc[m][n] = __builtin_amdgcn_mfma_f32_16x16x32_bf16(afr[m][1], bfr[n][1], acc[m][n], 0, 0, 0);
        uacc[m] = __builtin_amdgcn_mfma_f32_16x16x32_bf16(afr[m][1], wfrag[1], uacc[m], 0, 0, 0);
    }

    // ---- BN stats on fragments (channel == wave, 2048 elems) ----
    float s1 = 0.f, s2 = 0.f;
#pragma unroll
    for (int m = 0; m < 2; ++m)
#pragma unroll
        for (int n = 0; n < 4; ++n)
#pragma unroll
            for (int q = 0; q < 4; ++q) { float v = acc[m][n][q]; s1 += v; s2 += v*v; }
#pragma unroll
    for (int off = 1; off < 64; off <<= 1) {
        s1 += __shfl_xor(s1, off);
        s2 += __shfl_xor(s2, off);
    }
    const float mean = s1 * (1.f/2048.f);
    const float var  = s2 * (1.f/2048.f) - mean*mean;
    const float sc = ge[e] * rsqrtf(var + EPSI);
    const float sh = be[e] - mean*sc;

    // ---- normalize + ELU on fragments ----
#pragma unroll
    for (int m = 0; m < 2; ++m)
#pragma unroll
        for (int n = 0; n < 4; ++n)
#pragma unroll
            for (int q = 0; q < 4; ++q)
                acc[m][n][q] = elu(acc[m][n][q]*sc + sh);

    // ---- u store (col0 lanes hold u[b] for b = 16m+4lg+q) ----
    if (lr == 0) {
#pragma unroll
        for (int m = 0; m < 2; ++m)
#pragma unroll
            for (int q = 0; q < 4; ++q)
                uout[(size_t)(16*m + 4*lg + q)*EE + e] = uacc[m][q];
    }

    // ---- repack + store, 16-row halves through this wave's own LDS section ----
    float (*Z)[68] = reinterpret_cast<float (*)[68]>(&As[wv][0][0]);  // 4352B < 4608B section
    LGKM0();                              // fragment reads of As[wv] fully drained
#pragma unroll
    for (int h = 0; h < 2; ++h) {
#pragma unroll
        for (int n = 0; n < 4; ++n)
#pragma unroll
            for (int q = 0; q < 4; ++q)
                Z[4*lg + q][16*n + lr] = acc[h][n][q];
        LGKM0();                          // RAW: repack writes visible to reads
        if constexpr (OUTM == 0) {
            float* eout = (float*)eoutv;
#pragma unroll
            for (int it = 0; it < 4; ++it) {
                const int rr = lg + 4*it;            // 0..15
                const int b  = 16*h + rr;
                float4 z = *reinterpret_cast<float4*>(&Z[rr][lr*4]);
                *reinterpret_cast<float4*>(eout + ((size_t)b*EE + e)*DD + lr*4) = z;
            }
        } else {
            // store as next layer's A-fragments: row b=16h+rr, cols c0..c0+7
            // -> frag (m'=h, s'=(l&7)>>2), lane l' = rr + ((l&3)<<4)
            short* eoutp = (short*)eoutv + (size_t)e*BB*DD;
#pragma unroll
            for (int it = 0; it < 2; ++it) {
                const int rr = (l >> 3) + 8*it;      // 0..15
                const int c0 = (l & 7)*8;
                float4 zlo = *reinterpret_cast<float4*>(&Z[rr][c0]);
                float4 zhi = *reinterpret_cast<float4*>(&Z[rr][c0+4]);
                bf16x8 o;
                o[0]=f2bf(zlo.x); o[1]=f2bf(zlo.y); o[2]=f2bf(zlo.z); o[3]=f2bf(zlo.w);
                o[4]=f2bf(zhi.x); o[5]=f2bf(zhi.y); o[6]=f2bf(zhi.z); o[7]=f2bf(zhi.w);
                const int sp = (l & 7) >> 2;
                const int lp = rr + ((l & 3) << 4);
                *reinterpret_cast<bf16x8*>(eoutp + ((h*2 + sp)*64 + lp)*8) = o;
            }
        }
        LGKM0();                          // WAR: half-h reads done before h+1 overwrite
    }
}

// ---------------------------------------------------------------------------
// k_attn v2: per (b,i): logits = lrelu(s[j]+t[i]+u[b,i*N+j]) -> softmax over j
//   agg[b,i,:] = sum_j attn_j * zh[b,j,:]
// j-loop split into 4 independent accumulator chains (16 loads in flight).
__global__ void k_attn(const float* __restrict__ sI, const float* __restrict__ tI,
                       const float* __restrict__ u, const float* __restrict__ zh,
                       float* __restrict__ agg)
{
    int blk = blockIdx.x; int b = blk >> 7, i = blk & 127;
    int l = threadIdx.x;
    __shared__ float at[NN];
    float ti = tI[blk];
    float l0 = sI[b*NN + l]      + ti + u[b*EE + i*NN + l];
    float l1 = sI[b*NN + l + 64] + ti + u[b*EE + i*NN + l + 64];
    l0 = l0 >= 0.f ? l0 : 0.01f*l0;
    l1 = l1 >= 0.f ? l1 : 0.01f*l1;
    float mx = fmaxf(l0, l1);
#pragma unroll
    for (int off = 32; off; off >>= 1) mx = fmaxf(mx, __shfl_xor(mx, off));
    float e0 = __expf(l0 - mx), e1 = __expf(l1 - mx);
    float sm = e0 + e1;
#pragma unroll
    for (int off = 32; off; off >>= 1) sm += __shfl_xor(sm, off);
    float inv = 1.f / sm;
    at[l]      = e0 * inv;
    at[l + 64] = e1 * inv;
    __syncthreads();
    const float* zb = zh + (size_t)b*NN*DD + l;
    float a0 = 0.f, a1 = 0.f, a2 = 0.f, a3 = 0.f;
#pragma unroll 4
    for (int j = 0; j < NN; j += 4) {
        a0 += at[j]     * zb[(j)    *DD];
        a1 += at[j + 1] * zb[(j + 1)*DD];
        a2 += at[j + 2] * zb[(j + 2)*DD];
        a3 += at[j + 3] * zb[(j + 3)*DD];
    }
    agg[(b*NN + i)*DD + l] = (a0 + a1) + (a2 + a3);
}

// ---------------------------------------------------------------------------
// k_vbn: vertex BN (channel i over b,d) + residual + ELU
__global__ void k_vbn(const float* __restrict__ agg, const float* __restrict__ xres,
                      const float* __restrict__ gv, const float* __restrict__ bv,
                      float* __restrict__ xout)
{
    int i = blockIdx.x, t = threadIdx.x;
    float vals[8];
    float s1 = 0.f, s2 = 0.f;
#pragma unroll
    for (int q = 0; q < 8; ++q) {
        int m = t + 256*q; int b = m >> 6, d = m & 63;
        float v = agg[(b*NN + i)*DD + d];
        vals[q] = v; s1 += v; s2 += v*v;
    }
#pragma unroll
    for (int off = 1; off < 64; off <<= 1) {
        s1 += __shfl_xor(s1, off);
        s2 += __shfl_xor(s2, off);
    }
    __shared__ float r1[4], r2[4];
    int wv = t >> 6;
    if ((t & 63) == 0) { r1[wv] = s1; r2[wv] = s2; }
    __syncthreads();
    s1 = r1[0] + r1[1] + r1[2] + r1[3];
    s2 = r2[0] + r2[1] + r2[2] + r2[3];
    float mean  = s1 * (1.f/2048.f);
    float var   = s2 * (1.f/2048.f) - mean*mean;
    float scale = gv[i] * rsqrtf(var + EPSI);
    float shift = bv[i] - mean*scale;
#pragma unroll
    for (int q = 0; q < 8; ++q) {
        int m = t + 256*q; int b = m >> 6, d = m & 63;
        float v = vals[q]*scale + shift + xres[(b*NN + i)*DD + d];
        xout[(b*NN + i)*DD + d] = v > 0.f ? v : __expf(v) - 1.f;
    }
}

// ---------------------------------------------------------------------------
extern "C" void kernel_launch(void* const* d_in, const int* in_sizes, int n_in,
                              void* d_out, int out_size, void* d_ws, size_t ws_size,
                              hipStream_t stream)
{
    const float* x    = (const float*)d_in[0];
    const float* edge = (const float*)d_in[1];
    const float* Wh1  = (const float*)d_in[2];
    const float* We1  = (const float*)d_in[3];
    const float* Wp1  = (const float*)d_in[4];
    const float* Wa1  = (const float*)d_in[5];
    const float* Wh2  = (const float*)d_in[6];
    const float* We2  = (const float*)d_in[7];
    const float* Wp2  = (const float*)d_in[8];
    const float* Wa2  = (const float*)d_in[9];
    const float* gv1  = (const float*)d_in[10];
    const float* bv1  = (const float*)d_in[11];
    const float* ge1  = (const float*)d_in[12];
    const float* be1  = (const float*)d_in[13];
    const float* gv2  = (const float*)d_in[14];
    const float* bv2  = (const float*)d_in[15];
    const float* ge2  = (const float*)d_in[16];
    const float* be2  = (const float*)d_in[17];

    float* xout = (float*)d_out;                    // (B,N,D)
    float* eout = (float*)d_out + BB*NN*DD;         // (B,E,D) final edge output

    float* ws  = (float*)d_ws;
    short* MbT = (short*)ws;  ws += DD*DD/2;        // bf16 M fragment-major (8 KB)
    short* wfT = (short*)ws;  ws += 1024/2;         // bf16 w fragment-major (2 KB)
    float* zh  = ws;  ws += BB*NN*DD;
    float* PsT = ws;  ws += NN*BB*DD;               // fragment-layout Ps (1 MB)
    float* PdT = ws;  ws += NN*BB*DD;               // fragment-layout Pd (1 MB)
    float* sb  = ws;  ws += BB*NN;
    float* tb  = ws;  ws += BB*NN;
    float* ub  = ws;  ws += BB*EE;
    float* agg = ws;  ws += BB*NN*DD;
    float* x1  = ws;  ws += BB*NN*DD;
    short* ebf = (short*)ws;                        // A-frag-major intermediate (67 MB)
    const size_t need = ((size_t)(ws - (float*)d_ws))*4 + (size_t)EE*BB*DD*2;

    const bool dense = (ws_size >= need);

    // ----- layer 1 -----
    k_node<<<BB*NN + 64, 64, 0, stream>>>(x, Wh1, Wp1, We1, Wa1, zh, PsT, PdT, sb, tb, MbT, wfT);
    if (dense)
        k_edge<0,1><<<EE/4, 256, 0, stream>>>(edge, MbT, wfT, PsT, PdT, ge1, be1, ebf, ub);
    else
        k_edge<0,0><<<EE/4, 256, 0, stream>>>(edge, MbT, wfT, PsT, PdT, ge1, be1, eout, ub);
    k_attn<<<BB*NN, 64, 0, stream>>>(sb, tb, ub, zh, agg);
    k_vbn<<<NN, 256, 0, stream>>>(agg, x, gv1, bv1, x1);
    // ----- layer 2 -----
    k_node<<<BB*NN + 64, 64, 0, stream>>>(x1, Wh2, Wp2, We2, Wa2, zh, PsT, PdT, sb, tb, MbT, wfT);
    if (dense)
        k_edge<1,0><<<EE/4, 256, 0, stream>>>(ebf, MbT, wfT, PsT, PdT, ge2, be2, eout, ub);
    else  // in-place on eout: staged reads complete at __syncthreads before stores
        k_edge<0,0><<<EE/4, 256, 0, stream>>>(eout, MbT, wfT, PsT, PdT, ge2, be2, eout, ub);
    k_attn<<<BB*NN, 64, 0, stream>>>(sb, tb, ub, zh, agg);
    k_vbn<<<NN, 256, 0, stream>>>(agg, x1, gv2, bv2, xout);
}